// Round 8
// baseline (465.742 us; speedup 1.0000x reference)
//
#include <hip/hip_runtime.h>

#define W 1024
#define H 1024
#define PAD 4                         // halo/pad width (rows and cols)
#define XS 1032                       // padded row stride (floats)
#define YS 1032                       // padded row count
#define FR ((size_t)XS * (size_t)YS)  // floats per padded buffer
#define NPIX (H * W)
#define TRR 16                        // tile rows per block
#define TCC 64                        // tile cols per block
#define NBX 16                        // col tiles
#define NBY 64                        // row tiles (grid = 1024 blocks)
#define RROWS 24                      // region rows = TRR + 2*PAD
#define RCOLS 72                      // region cols = TCC + 2*PAD
#define LST 80                        // LDS row stride: pads at [0,4) and [76,80)
#define LBUF (RROWS * LST)            // 1920 floats per h buffer (7.5 KB)
#define NSLOT 396                     // 22 rows x 18 col-groups (4 px each)
#define NT 448                        // 7 waves
#define LOG2E 1.4426950408889634f
#define TWOL  2.8853900817779268f     // 2*log2(e)

typedef float v2f __attribute__((ext_vector_type(2)));

__device__ __forceinline__ float frcp_(float v) { return __builtin_amdgcn_rcpf(v); }
__device__ __forceinline__ float exp2_(float v) { return __builtin_amdgcn_exp2f(v); }

// Zero one slack row + the 6 padded state buffers (ws[0..XS+6FR)) and write
// log2e-scaled weights after them. The slack row (ws[0..XS)) makes the decoder
// x-hoist's p[-1] read at padded (row 0, col -1) a mapped ZERO -- the exact
// SAME-pad value (R7 crashed on this read going 1 float before the buffer).
// Gate pre-activations i,f,o scaled by log2(e), g by 2*log2(e).
__global__ __launch_bounds__(256) void init_ws(const float* __restrict__ ew,
                                               const float* __restrict__ eb,
                                               const float* __restrict__ dw,
                                               const float* __restrict__ db,
                                               float* __restrict__ ws) {
    const size_t n4 = (XS + 6 * FR) / 4;
    size_t i = (size_t)blockIdx.x * blockDim.x + threadIdx.x;
    const size_t stride = (size_t)gridDim.x * blockDim.x;
    float4* w4 = (float4*)ws;
    const float4 z = make_float4(0.f, 0.f, 0.f, 0.f);
    for (; i < n4; i += stride) w4[i] = z;
    if (blockIdx.x == 0) {
        float* wsc = ws + XS + 6 * FR;
        const int t = threadIdx.x;
        if (t < 72)                   wsc[t] = ew[t] * ((t / 18 == 3) ? TWOL : LOG2E);
        else if (t < 76)              wsc[t] = eb[t - 72] * ((t - 72 == 3) ? TWOL : LOG2E);
        else if (t >= 80 && t < 152)  wsc[t] = dw[t - 80] * (((t - 80) / 18 == 3) ? TWOL : LOG2E);
        else if (t >= 152 && t < 156) wsc[t] = db[t - 152] * ((t - 152 == 3) ? TWOL : LOG2E);
    }
}

// One conv-input row for a 4-px slot: 6 floats (cols c-1 .. c+4).
// Accumulate the 3-tap row for all 4 gates into acc[4][2] (2 output pairs).
// Pair vectors shared across gates -> v_pk_fma_f32.
__device__ __forceinline__ void acc_row4(float lm, float4 m, float rp,
                                         const float* __restrict__ wg, int wofs,
                                         v2f acc[4][2]) {
    const v2f E0 = {m.x, m.y}, E1 = {m.z, m.w};
    const v2f O0 = {lm, m.x}, O1 = {m.y, m.z}, O2 = {m.w, rp};
#pragma unroll
    for (int co = 0; co < 4; ++co) {
        const float w0 = wg[co * 18 + wofs + 0];
        const float w1 = wg[co * 18 + wofs + 1];
        const float w2 = wg[co * 18 + wofs + 2];
        const v2f W0 = {w0, w0}, W1 = {w1, w1}, W2 = {w2, w2};
        acc[co][0] += W0 * O0 + W1 * E0 + W2 * O1;
        acc[co][1] += W0 * O1 + W1 * E1 + W2 * O2;
    }
}

// Masked raw-frame row load (SAME zero padding at image borders).
// gc0 is a multiple of 4, so the float4 is fully in- or out-of-image.
struct XR { float lm; float4 m; float rp; };
__device__ __forceinline__ XR ldx4(const float* __restrict__ fr, int ry, int gc0) {
    XR r; r.m = make_float4(0.f, 0.f, 0.f, 0.f); r.lm = 0.f; r.rp = 0.f;
    if ((unsigned)ry < (unsigned)H) {
        const float* p = fr + (size_t)ry * W + gc0;
        if ((unsigned)gc0 < (unsigned)W)       r.m  = *(const float4*)p;
        if ((unsigned)(gc0 - 1) < (unsigned)W) r.lm = p[-1];
        if ((unsigned)(gc0 + 4) < (unsigned)W) r.rp = p[4];
    }
    return r;
}

// 4 fused conv-LSTM steps. Grid 1024 (64 row-tiles x 16 col-tiles, 16x64
// interior each), 448 threads (7 waves), 4 px/thread. OCCUPANCY is the lever:
// 21-28 waves/CU (was 16). waves_per_eu(6,7): min 6 caps VGPR ~85 -- generous
// above the ~60-reg natural pressure of the 4-px state, so no spill cliff
// (R2/R4 lesson), while allowing 4 blocks/CU (28 waves) if pressure <= 72.
// LDS 15.4KB/blk. Region 24x72 for 16x64 interior = 1.69x redundancy (was
// 2.25x). Per step: act-gated rows [i, 24-i); col pollution creeps 1/step
// into the 4-col halo, interior [4,68) safe at step 4. LDS row pads ([0,4),
// [76,80), zeroed once, never written) serve region-edge reads as zeros.
// Gates rcp-fused: 5 exp2 + 2 rcp per px (R5-verified, absmax 4.9e-4).
template<bool XC>
__global__ __launch_bounds__(NT)
__attribute__((amdgpu_waves_per_eu(6, 7)))
void fused4(const float* __restrict__ xbase, size_t xstep,
            const float* __restrict__ hin, const float* __restrict__ cin,
            float* __restrict__ hout, float* __restrict__ cout_,
            const float* __restrict__ wg, const float* __restrict__ bg,
            float* __restrict__ dout, int zero_init)
{
    __shared__ float hT[2 * LBUF];
    const int tid = threadIdx.x;
    const int bx = blockIdx.x & (NBX - 1);
    const int by = blockIdx.x >> 4;
    const int c0 = bx * TCC, r0 = by * TRR;

    const bool has = tid < NSLOT;
    const int q    = tid / 18;            // 0..21
    const int g    = tid - q * 18;        // col group 0..17
    const int lrow = 1 + q;               // local row 1..22
    const int lcol = 4 * g;               // logical col 0..68
    const int gr   = r0 - PAD + lrow;     // global row
    const int gc0  = c0 - PAD + lcol;     // global col (multiple of 4)
    const size_t gofs = (size_t)(gr + PAD) * XS + (gc0 + PAD);
    const bool inimg = ((unsigned)gr < (unsigned)H) && ((unsigned)gc0 < (unsigned)W);
    // raw-x fast path: rows [r0-4, r0+19], cols [gc0-1, gc0+4] all in-image
    const bool safe = (r0 >= 4) && (r0 + 20 <= H) && (c0 >= 5) && (c0 + 69 <= W);

    // ---- initial LDS: buf0 = h region (or 0), buf1 = 0; pads stay 0 ----
    for (int idx = tid; idx < 2 * RROWS * (LST / 4); idx += NT) {
        const int b   = idx / (RROWS * (LST / 4));
        const int k   = idx - b * (RROWS * (LST / 4));
        const int row = k / (LST / 4);
        const int ch  = k - row * (LST / 4);    // 0..19; px chunks 1..18
        float4 v = make_float4(0.f, 0.f, 0.f, 0.f);
        if (b == 0 && !zero_init && ch >= 1 && ch <= 18)
            v = *(const float4*)(hin + (size_t)(r0 + row) * XS + (c0 + 4 * (ch - 1)));
        *(float4*)(&hT[b * LBUF + row * LST + 4 * ch]) = v;
    }

    // ---- c state in registers ----
    float cc[4], hh[4];
    if (has && !zero_init) {
        const float4 a = *(const float4*)(cin + gofs);
        cc[0] = a.x; cc[1] = a.y; cc[2] = a.z; cc[3] = a.w;
    } else {
#pragma unroll
        for (int e = 0; e < 4; ++e) cc[e] = 0.f;
    }
#pragma unroll
    for (int e = 0; e < 4; ++e) hh[e] = 0.f;

    // ---- decoder: hoist constant x-channel conv + bias (8 VGPRs) ----
    v2f xacc[4][2];
    if constexpr (XC) {
        if (has) {
#pragma unroll
            for (int co = 0; co < 4; ++co) {
                const v2f bb = {bg[co], bg[co]};
                xacc[co][0] = bb; xacc[co][1] = bb;
            }
            const float* p = xbase + gofs - XS;
            acc_row4(p[-1], *(const float4*)p, p[4], wg, 0, xacc);
            p += XS;
            acc_row4(p[-1], *(const float4*)p, p[4], wg, 3, xacc);
            p += XS;
            acc_row4(p[-1], *(const float4*)p, p[4], wg, 6, xacc);
        }
    }
    __syncthreads();

#pragma unroll
    for (int i = 1; i <= 4; ++i) {
        const float* hR = hT + ((i + 1) & 1) * LBUF;   // h_{i-1}
        float* hW       = hT + (i & 1) * LBUF;         // receives h_i
        const bool act = has && (lrow >= i) && (lrow < RROWS - i);
        if (act) {
            // issue all 9 LDS reads first; latency hides under the convs
            const int o1 = lrow * LST + 4 + lcol;
            const int o0 = o1 - LST, o2 = o1 + LST;
            const float4 A0 = *(const float4*)(hR + o0);
            const float4 A1 = *(const float4*)(hR + o1);
            const float4 A2 = *(const float4*)(hR + o2);
            const float L0 = hR[o0 - 1], P0 = hR[o0 + 4];
            const float L1 = hR[o1 - 1], P1 = hR[o1 + 4];
            const float L2 = hR[o2 - 1], P2 = hR[o2 + 4];

            v2f acc[4][2];
            if constexpr (XC) {
#pragma unroll
                for (int co = 0; co < 4; ++co) {
                    acc[co][0] = xacc[co][0]; acc[co][1] = xacc[co][1];
                }
            } else {
#pragma unroll
                for (int co = 0; co < 4; ++co) {
                    const v2f bb = {bg[co], bg[co]};
                    acc[co][0] = bb; acc[co][1] = bb;
                }
                const float* xf = xbase + (size_t)(i - 1) * xstep;
                if (safe) {
                    const float* p = xf + (size_t)(gr - 1) * W + gc0;
                    acc_row4(p[-1], *(const float4*)p, p[4], wg, 0, acc);
                    p += W;
                    acc_row4(p[-1], *(const float4*)p, p[4], wg, 3, acc);
                    p += W;
                    acc_row4(p[-1], *(const float4*)p, p[4], wg, 6, acc);
                } else {
                    const XR x0 = ldx4(xf, gr - 1, gc0);
                    acc_row4(x0.lm, x0.m, x0.rp, wg, 0, acc);
                    const XR x1 = ldx4(xf, gr, gc0);
                    acc_row4(x1.lm, x1.m, x1.rp, wg, 3, acc);
                    const XR x2 = ldx4(xf, gr + 1, gc0);
                    acc_row4(x2.lm, x2.m, x2.rp, wg, 6, acc);
                }
            }
            acc_row4(L0, A0, P0, wg, 9, acc);
            acc_row4(L1, A1, P1, wg, 12, acc);
            acc_row4(L2, A2, P2, wg, 15, acc);

            // ---- rcp-fused gates: 5 exp2 + 2 rcp per px ----
            // cn = [c(1+Eg)(1+Ei) + (Eg-1)(1+Ef)] / [(1+Ef)(1+Eg)(1+Ei)]
            // h  = (Ec-1) / ((1+Eo)(1+Ec)),  Ec = 2^(2log2e * cn)
#pragma unroll
            for (int jp = 0; jp < 2; ++jp) {
#pragma unroll
                for (int s = 0; s < 2; ++s) {
                    const int e = 2 * jp + s;
                    const float Ei = exp2_(-acc[0][jp][s]);
                    const float Ef = exp2_(-acc[1][jp][s]);
                    const float Eo = exp2_(-acc[2][jp][s]);
                    const float Eg = exp2_(acc[3][jp][s]);
                    const float Pp = (1.f + Eg) * (1.f + Ei);
                    const float Qq = 1.f + Ef;
                    const float cn = (cc[e] * Pp + (Eg - 1.f) * Qq) * frcp_(Pp * Qq);
                    cc[e] = cn;
                    const float Ec = exp2_(TWOL * cn);
                    const float hv = (Ec - 1.f) * frcp_((1.f + Eo) * (1.f + Ec));
                    hh[e] = inimg ? hv : 0.f;   // SAME zero-pad
                }
            }
            *(float4*)(hW + o1) = make_float4(hh[0], hh[1], hh[2], hh[3]);
        }
        __syncthreads();   // h_i visible; next step writes the other buffer
    }

    // ---- interior write-out: rows lrow in [4,20), groups g in [1,16] ----
    if (has && lrow >= PAD && lrow < PAD + TRR && g >= 1 && g <= 16) {
        if (dout) {
            *(float4*)(dout + (size_t)gr * W + gc0) =
                make_float4(hh[0], hh[1], hh[2], hh[3]);
        } else {
            *(float4*)(hout + gofs)  = make_float4(hh[0], hh[1], hh[2], hh[3]);
            *(float4*)(cout_ + gofs) = make_float4(cc[0], cc[1], cc[2], cc[3]);
        }
    }
}

extern "C" void kernel_launch(void* const* d_in, const int* in_sizes, int n_in,
                              void* d_out, int out_size, void* d_ws, size_t ws_size,
                              hipStream_t stream) {
    const float* data  = (const float*)d_in[0];  // [20,1,1,1024,1024]
    const float* enc_w = (const float*)d_in[1];  // [4,2,3,3]
    const float* enc_b = (const float*)d_in[2];  // [4]
    const float* dec_w = (const float*)d_in[3];
    const float* dec_b = (const float*)d_in[4];
    // d_in[5..7] = epoch(0), T_en(20), T_de(20): constant device scalars;
    // loop counts hardcoded (host can't read device memory under capture).

    float* ws  = (float*)d_ws;
    float* sb  = ws + XS;                 // buffers start after 1 slack row
    float* hE1 = sb + 0 * FR;
    float* cE1 = sb + 1 * FR;
    float* hE0 = sb + 2 * FR;
    float* cE0 = sb + 3 * FR;
    float* hX  = sb + 4 * FR;
    float* cX  = sb + 5 * FR;
    float* wsc = sb + 6 * FR;             // scaled weights/biases (156 floats)
    const float* encW = wsc;
    const float* encB = wsc + 72;
    const float* decW = wsc + 80;
    const float* decB = wsc + 152;
    float* dout = (float*)d_out;
    // ws use: (XS + 6*FR)*4 + 1KB ~= 25.6 MB

    init_ws<<<2048, 256, 0, stream>>>(enc_w, enc_b, dec_w, dec_b, ws);

    dim3 blk(NT), grd(NBX * NBY);
    const size_t xf4 = (size_t)4 * NPIX;
    // encoder: 5 x 4 steps (x read raw from data)
    fused4<false><<<grd, blk, 0, stream>>>(data,           (size_t)NPIX,
                                           nullptr, nullptr, hE1, cE1, encW, encB, nullptr, 1);
    fused4<false><<<grd, blk, 0, stream>>>(data + 1 * xf4, (size_t)NPIX,
                                           hE1, cE1, hE0, cE0, encW, encB, nullptr, 0);
    fused4<false><<<grd, blk, 0, stream>>>(data + 2 * xf4, (size_t)NPIX,
                                           hE0, cE0, hE1, cE1, encW, encB, nullptr, 0);
    fused4<false><<<grd, blk, 0, stream>>>(data + 3 * xf4, (size_t)NPIX,
                                           hE1, cE1, hE0, cE0, encW, encB, nullptr, 0);
    fused4<false><<<grd, blk, 0, stream>>>(data + 4 * xf4, (size_t)NPIX,
                                           hE0, cE0, hE1, cE1, encW, encB, nullptr, 0);
    // final encoder h in hE1 (constant decoder input; preserved through dec)
    fused4<true><<<grd, blk, 0, stream>>>(hE1, 0, nullptr, nullptr,
                                          hX, cX, decW, decB, nullptr, 1);
    fused4<true><<<grd, blk, 0, stream>>>(hE1, 0, hX, cX,
                                          hE0, cE0, decW, decB, nullptr, 0);
    fused4<true><<<grd, blk, 0, stream>>>(hE1, 0, hE0, cE0,
                                          hX, cX, decW, decB, nullptr, 0);
    fused4<true><<<grd, blk, 0, stream>>>(hE1, 0, hX, cX,
                                          hE0, cE0, decW, decB, nullptr, 0);
    fused4<true><<<grd, blk, 0, stream>>>(hE1, 0, hE0, cE0,
                                          nullptr, nullptr, decW, decB, dout, 0);
}

// Round 9
// 338.196 us; speedup vs baseline: 1.3771x; 1.3771x over previous
//
#include <hip/hip_runtime.h>

#define W 1024
#define H 1024
#define PADX 16                       // col zero-pad each side (state/h buffers)
#define PADY 8                        // row zero-pad each side
#define XS 1056                       // padded row stride (floats)
#define YS 1040                       // padded row count
#define FR ((size_t)XS * (size_t)YS)  // floats per padded buffer
#define NPIX (H * W)
#define TROWS 32                      // tile rows per block
#define TCOLS 64                      // tile cols per block
#define LRN 48                        // local rows: gr in [r0-8, r0+40)
#define LCV 96                        // valid local cols: gc in [c0-16, c0+80)
#define LCW 100                       // LDS row stride (pad 4 to stagger banks)
#define NSLOT 460                     // 46 rows x 10 col-groups (8 px each)
#define NB 512
#define LOG2E 1.4426950408889634f
#define TWOL  2.8853900817779268f     // 2*log2(e)

typedef float v2f __attribute__((ext_vector_type(2)));

__device__ __forceinline__ float frcp_(float v) { return __builtin_amdgcn_rcpf(v); }
__device__ __forceinline__ float exp2_(float v) { return __builtin_amdgcn_exp2f(v); }

// Border-only workspace init + scaled weights.
// Only the pad borders of the 6 state buffers are ever read without being
// written (every interior cell is producer-written before consumer-read), so
// zero just rows [0,8)+[1032,1040) full width and cols [0,16)+[1040,1056) of
// the interior rows: 12416 float4/buffer (was 274560) -> init cost ~1/20.
// Weights at ws+6FR: enc_w[0..72) enc_b[72..76) dec_w[80..152) dec_b[152..156),
// i,f,o rows scaled by log2(e), g row by 2*log2(e) (exp2 needs no per-element
// multiply in the gate math).
__global__ __launch_bounds__(256) void init_ws(const float* __restrict__ ew,
                                               const float* __restrict__ eb,
                                               const float* __restrict__ dw,
                                               const float* __restrict__ db,
                                               float* __restrict__ ws) {
    const int NBF = 12416;            // border float4s per buffer
    float4* w4 = (float4*)ws;
    const float4 z = make_float4(0.f, 0.f, 0.f, 0.f);
    for (int i = blockIdx.x * 256 + threadIdx.x; i < 6 * NBF;
         i += gridDim.x * 256) {
        const int b = i / NBF;
        const int j = i - b * NBF;
        int r, c4;
        if (j < 2112)      { r = j / 264;                    c4 = j - 264 * r; }        // top 8 rows
        else if (j < 4224) { const int k = j - 2112; r = 1032 + k / 264; c4 = k % 264; } // bottom 8 rows
        else if (j < 8320) { const int k = j - 4224; r = 8 + (k >> 2);   c4 = k & 3; }   // left 16 cols
        else               { const int k = j - 8320; r = 8 + (k >> 2);   c4 = 260 + (k & 3); } // right 16 cols
        w4[(size_t)b * (FR / 4) + (size_t)r * (XS / 4) + c4] = z;
    }
    if (blockIdx.x == 0) {
        float* wsc = ws + 6 * FR;
        const int t = threadIdx.x;
        if (t < 72)                   wsc[t] = ew[t] * ((t / 18 == 3) ? TWOL : LOG2E);
        else if (t < 76)              wsc[t] = eb[t - 72] * ((t - 72 == 3) ? TWOL : LOG2E);
        else if (t >= 80 && t < 152)  wsc[t] = dw[t - 80] * (((t - 80) / 18 == 3) ? TWOL : LOG2E);
        else if (t >= 152 && t < 156) wsc[t] = db[t - 152] * ((t - 152 == 3) ? TWOL : LOG2E);
    }
}

// Accumulate one 3-tap conv row over an 8-px slot into acc[4][4] (output pairs).
// Pair vectors built once per row, shared across the 4 gates -> v_pk_fma_f32.
__device__ __forceinline__ void acc_row(float4 A, float4 Bq, float lm, float rp,
                                        const float* __restrict__ wg, int wofs, int dy,
                                        v2f acc[4][4]) {
    const v2f E0 = {A.x, A.y},  E1 = {A.z, A.w};
    const v2f E2 = {Bq.x, Bq.y}, E3 = {Bq.z, Bq.w};
    const v2f O0 = {lm, A.x},   O1 = {A.y, A.z};
    const v2f O2 = {A.w, Bq.x}, O3 = {Bq.y, Bq.z}, O4 = {Bq.w, rp};
#pragma unroll
    for (int co = 0; co < 4; ++co) {
        const float w0 = wg[co * 18 + wofs + dy * 3 + 0];
        const float w1 = wg[co * 18 + wofs + dy * 3 + 1];
        const float w2 = wg[co * 18 + wofs + dy * 3 + 2];
        const v2f W0 = {w0, w0}, W1 = {w1, w1}, W2 = {w2, w2};
        acc[co][0] += W0 * O0 + W1 * E0 + W2 * O1;
        acc[co][1] += W0 * O1 + W1 * E1 + W2 * O2;
        acc[co][2] += W0 * O2 + W1 * E2 + W2 * O3;
        acc[co][3] += W0 * O3 + W1 * E3 + W2 * O4;
    }
}

// Unchecked 3-row conv of one channel; p = slot top-left (row gr-1, col gc0).
__device__ __forceinline__ void conv3x8_pk(const float* __restrict__ p, int stride,
                                           const float* __restrict__ wg, int wofs,
                                           v2f acc[4][4]) {
#pragma unroll
    for (int dy = 0; dy < 3; ++dy) {
        acc_row(*(const float4*)p, *(const float4*)(p + 4), p[-1], p[8], wg, wofs, dy, acc);
        p += stride;
    }
}

// Boundary-checked conv over the RAW (unpadded) x frame: SAME zero padding via
// masked loads. gc0 is a multiple of 8, so the float4 pair is all-in or all-out.
__device__ __forceinline__ void conv3x8_edge(const float* __restrict__ base, int gr, int gc0,
                                             const float* __restrict__ wg, int wofs,
                                             v2f acc[4][4]) {
    const bool colA = (unsigned)gc0 < (unsigned)W;
    const bool lmok = (unsigned)(gc0 - 1) < (unsigned)W;
    const bool rpok = (unsigned)(gc0 + 8) < (unsigned)W;
#pragma unroll
    for (int dy = 0; dy < 3; ++dy) {
        const int ry = gr - 1 + dy;
        const bool rok = (unsigned)ry < (unsigned)H;
        const float* row = base + (long)ry * W;
        float4 A = make_float4(0.f, 0.f, 0.f, 0.f);
        float4 Bq = make_float4(0.f, 0.f, 0.f, 0.f);
        float lm = 0.f, rp = 0.f;
        if (rok) {
            if (colA) { A = *(const float4*)(row + gc0); Bq = *(const float4*)(row + gc0 + 4); }
            if (lmok) lm = row[gc0 - 1];
            if (rpok) rp = row[gc0 + 8];
        }
        acc_row(A, Bq, lm, rp, wg, wofs, dy, acc);
    }
}

// NSTEPS fused conv-LSTM steps. EXACT R1 skeleton (the 350us equilibrium:
// 512 blocks x 512 threads = 2 blocks/CU, 56-64 VGPR no-spill, LCW=100,
// x-conv then h-conv with inline LDS reads, direct acc init, no setprio,
// waves_per_eu(4,4) load-bearing) with ONE change: the gate tail is
// rcp-fused (5 exp2 + 2 rcp per px instead of 5+5; R5/R6-verified
// numerically, absmax 4.9e-4).
template<int NSTEPS, bool XC>
__global__ __launch_bounds__(NB)
__attribute__((amdgpu_waves_per_eu(4, 4)))
void fusedN(const float* __restrict__ xbase, size_t xstep,
            const float* __restrict__ hin, const float* __restrict__ cin,
            float* __restrict__ hout, float* __restrict__ cout_,
            const float* __restrict__ wg, const float* __restrict__ bg,
            float* __restrict__ dout, int zero_init)
{
    __shared__ float hT[2][LRN * LCW];
    const int tid = threadIdx.x;
    const int c0 = (blockIdx.x & 15) * TCOLS;
    const int r0 = (blockIdx.x >> 4) * TROWS;

    const bool has = tid < NSLOT;
    const int q   = tid / 10;             // slot row index 0..45
    const int jj  = tid - q * 10;         // col group 0..9
    const int lr  = 1 + q;                // local row 1..46
    const int lc  = 8 + 8 * jj;           // local col 8..80
    const int gr  = r0 - 8 + lr;          // global row of slot
    const int gc0 = c0 - 8 + 8 * jj;      // global col of slot (multiple of 8)
    const size_t gofs = (size_t)(gr + PADY) * XS + (gc0 + PADX);
    const bool inimg = ((unsigned)gr < (unsigned)H) && ((unsigned)gc0 < (unsigned)W);
    // raw-x fast path: all taps in rows [r0-9, r0+40], cols [c0-9, c0+80]
    const bool safe = (r0 >= 8) && (r0 + 40 <= H) && (c0 >= 16) && (c0 + 80 <= W);

    // ---- initial LDS h tile into buf0 (buf1 zeroed for hygiene) ----
    for (int idx = tid; idx < LRN * (LCV / 4); idx += NB) {
        const int r = idx / (LCV / 4);
        const int k = idx - r * (LCV / 4);
        float4 v = make_float4(0.f, 0.f, 0.f, 0.f);
        if (!zero_init)
            v = *(const float4*)(hin + (size_t)(r0 + r) * XS + (c0 + 4 * k));
        *(float4*)(&hT[0][r * LCW + 4 * k]) = v;
        *(float4*)(&hT[1][r * LCW + 4 * k]) = make_float4(0.f, 0.f, 0.f, 0.f);
    }

    // ---- c state in registers ----
    float cc[8];
    if (has && !zero_init) {
        const float4 a = *(const float4*)(cin + gofs);
        const float4 b = *(const float4*)(cin + gofs + 4);
        cc[0] = a.x; cc[1] = a.y; cc[2] = a.z; cc[3] = a.w;
        cc[4] = b.x; cc[5] = b.y; cc[6] = b.z; cc[7] = b.w;
    } else {
#pragma unroll
        for (int e = 0; e < 8; ++e) cc[e] = 0.f;
    }

    // ---- decoder: hoist constant x-channel conv + bias into registers ----
    v2f xacc[4][4];
    if constexpr (XC) {
        if (has) {
#pragma unroll
            for (int co = 0; co < 4; ++co) {
                const v2f bb = {bg[co], bg[co]};
#pragma unroll
                for (int j = 0; j < 4; ++j) xacc[co][j] = bb;
            }
            conv3x8_pk(xbase + gofs - XS, XS, wg, 0, xacc);
        }
    }
    __syncthreads();

    float hh[8];
#pragma unroll
    for (int e = 0; e < 8; ++e) hh[e] = 0.f;

#pragma unroll
    for (int i = 1; i <= NSTEPS; ++i) {
        const float* hR = hT[(i + 1) & 1];   // holds h_{i-1}
        float* hW       = hT[i & 1];         // receives h_i
        const bool act = has && (lr >= i) && (lr < LRN - i);
        if (act) {
            v2f acc[4][4];
            if constexpr (XC) {
#pragma unroll
                for (int co = 0; co < 4; ++co)
#pragma unroll
                    for (int j = 0; j < 4; ++j) acc[co][j] = xacc[co][j];
            } else {
#pragma unroll
                for (int co = 0; co < 4; ++co) {
                    const v2f bb = {bg[co], bg[co]};
#pragma unroll
                    for (int j = 0; j < 4; ++j) acc[co][j] = bb;
                }
                const float* xp = xbase + (size_t)(i - 1) * xstep;
                if (safe)
                    conv3x8_pk(xp + (size_t)(gr - 1) * W + gc0, W, wg, 0, acc);
                else
                    conv3x8_edge(xp, gr, gc0, wg, 0, acc);
            }
            conv3x8_pk(hR + (lr - 1) * LCW + lc, LCW, wg, 9, acc);

            // ---- rcp-fused gates: 5 exp2 + 2 rcp per px (was 5+5) ----
            // cn = [c(1+Eg)(1+Ei) + (Eg-1)(1+Ef)] / [(1+Ef)(1+Eg)(1+Ei)]
            // h  = (Ec-1) / ((1+Eo)(1+Ec)),  Ec = 2^(2log2e * cn)
#pragma unroll
            for (int jp = 0; jp < 4; ++jp) {
#pragma unroll
                for (int s = 0; s < 2; ++s) {
                    const int e = 2 * jp + s;
                    const float Ei = exp2_(-acc[0][jp][s]);
                    const float Ef = exp2_(-acc[1][jp][s]);
                    const float Eo = exp2_(-acc[2][jp][s]);
                    const float Eg = exp2_(acc[3][jp][s]);
                    const float Pp = (1.f + Eg) * (1.f + Ei);
                    const float Qq = 1.f + Ef;
                    const float cn = (cc[e] * Pp + (Eg - 1.f) * Qq) * frcp_(Pp * Qq);
                    cc[e] = cn;
                    const float Ec = exp2_(TWOL * cn);
                    const float hv = (Ec - 1.f) * frcp_((1.f + Eo) * (1.f + Ec));
                    hh[e] = inimg ? hv : 0.f;   // SAME zero-pad
                }
            }
            *(float4*)(hW + lr * LCW + lc)     = make_float4(hh[0], hh[1], hh[2], hh[3]);
            *(float4*)(hW + lr * LCW + lc + 4) = make_float4(hh[4], hh[5], hh[6], hh[7]);
        }
        __syncthreads();   // h_i visible; next step writes the other buffer
    }

    // ---- interior write-out: rows lr in [8,40), col groups jj in [1,8] ----
    if (has && lr >= 8 && lr < 8 + TROWS && jj >= 1 && jj <= 8) {
        if (dout) {
            const size_t o = (size_t)gr * W + gc0;
            *(float4*)(dout + o)     = make_float4(hh[0], hh[1], hh[2], hh[3]);
            *(float4*)(dout + o + 4) = make_float4(hh[4], hh[5], hh[6], hh[7]);
        } else {
            *(float4*)(hout + gofs)      = make_float4(hh[0], hh[1], hh[2], hh[3]);
            *(float4*)(hout + gofs + 4)  = make_float4(hh[4], hh[5], hh[6], hh[7]);
            *(float4*)(cout_ + gofs)     = make_float4(cc[0], cc[1], cc[2], cc[3]);
            *(float4*)(cout_ + gofs + 4) = make_float4(cc[4], cc[5], cc[6], cc[7]);
        }
    }
}

extern "C" void kernel_launch(void* const* d_in, const int* in_sizes, int n_in,
                              void* d_out, int out_size, void* d_ws, size_t ws_size,
                              hipStream_t stream) {
    const float* data  = (const float*)d_in[0];  // [20,1,1,1024,1024]
    const float* enc_w = (const float*)d_in[1];  // [4,2,3,3]
    const float* enc_b = (const float*)d_in[2];  // [4]
    const float* dec_w = (const float*)d_in[3];
    const float* dec_b = (const float*)d_in[4];
    // d_in[5..7] = epoch(0), T_en(20), T_de(20): constant device scalars;
    // loop counts hardcoded (host can't read device memory under capture).

    float* ws  = (float*)d_ws;
    float* hE1 = ws + 0 * FR;
    float* cE1 = ws + 1 * FR;
    float* hE0 = ws + 2 * FR;
    float* cE0 = ws + 3 * FR;
    float* hX  = ws + 4 * FR;
    float* cX  = ws + 5 * FR;
    float* wsc = ws + 6 * FR;             // scaled weights/biases (156 floats)
    const float* encW = wsc;
    const float* encB = wsc + 72;
    const float* decW = wsc + 80;
    const float* decB = wsc + 152;
    float* dout = (float*)d_out;
    // ws use: 6*FR*4 + 1KB ~= 26.4 MB (x read raw; only pad borders zeroed)

    init_ws<<<512, 256, 0, stream>>>(enc_w, enc_b, dec_w, dec_b, ws);

    dim3 blk(NB), grd(512);
    // encoder: steps 0-7, 8-15, 16-19 (x read raw from data)
    fusedN<8, false><<<grd, blk, 0, stream>>>(data,                     (size_t)NPIX,
                                              nullptr, nullptr, hE1, cE1, encW, encB, nullptr, 1);
    fusedN<8, false><<<grd, blk, 0, stream>>>(data + (size_t)8 * NPIX,  (size_t)NPIX,
                                              hE1, cE1, hE0, cE0, encW, encB, nullptr, 0);
    fusedN<4, false><<<grd, blk, 0, stream>>>(data + (size_t)16 * NPIX, (size_t)NPIX,
                                              hE0, cE0, hE1, cE1, encW, encB, nullptr, 0);
    // final encoder h in hE1 (constant decoder input; zero halo ring = SAME pad)
    fusedN<8, true><<<grd, blk, 0, stream>>>(hE1, 0, nullptr, nullptr,
                                             hE0, cE0, decW, decB, nullptr, 1);
    fusedN<8, true><<<grd, blk, 0, stream>>>(hE1, 0, hE0, cE0,
                                             hX,  cX,  decW, decB, nullptr, 0);
    fusedN<4, true><<<grd, blk, 0, stream>>>(hE1, 0, hX,  cX,
                                             nullptr, nullptr, decW, decB, dout, 0);
}